// Round 8
// baseline (106.552 us; speedup 1.0000x reference)
//
#include <hip/hip_runtime.h>
#include <math.h>

#define PATCHES 196
#define KPAD 800                 // 784 padded to 25*32 for MFMA K-loop
#define MROWS 8                  // batch rows per block
#define CIRC (MROWS * PATCHES)   // 1568 circuits per block
#define THREADS 512
#define FRAG_ELEMS (25 * 64 * 8) // full 16-row A-frag (rows 8..15 zeroed)
#define P2_REPS 8                // ATTRIBUTION: phase-2 K-loop x8 (exact math)

typedef short short8 __attribute__((ext_vector_type(8)));
typedef float f32x4 __attribute__((ext_vector_type(4)));

__device__ __forceinline__ unsigned short f2bf(float f) {
  union { float f; unsigned u; } x; x.f = f;
  unsigned r = x.u + 0x7fff + ((x.u >> 16) & 1);  // round-to-nearest-even
  return (unsigned short)(r >> 16);
}

// ---------------------------------------------------------------------------
// Stage 0: pack W1^T (bf16, K zero-padded) into B-fragment order:
// elem = ntile*FRAG_ELEMS + (ki*64 + quad*16 + n15)*8 + j  (lane-contiguous)
// ---------------------------------------------------------------------------
__global__ __launch_bounds__(256) void w1t_pack_kernel(
    const float* __restrict__ W1, unsigned short* __restrict__ w1p) {
  int idx = blockIdx.x * 256 + threadIdx.x;
  if (idx >= 128 * KPAD) return;
  int n = idx / KPAD;
  int k = idx - n * KPAD;
  float v = (k < 784) ? W1[k * 128 + n] : 0.f;
  int ki = k >> 5;
  int quad = (k & 31) >> 3;
  int j = k & 7;
  w1p[(n >> 4) * FRAG_ELEMS + (ki * 64 + quad * 16 + (n & 15)) * 8 + j] = f2bf(v);
}

// ---------------------------------------------------------------------------
// Fused kernel, ATTRIBUTION BUILD 2: phase-2 K-loop executed P2_REPS times
// into one accumulator, scaled by 1/P2_REPS (exact: identical reps, pow-2
// scale). asm-opaque zero offset defeats LICM/CSE/DCE across reps.
// Everything else IDENTICAL to R7 for clean subtraction.
// ---------------------------------------------------------------------------
__device__ __forceinline__ void apply_ry(float st[16], int bit, float c, float s) {
#pragma unroll
  for (int i = 0; i < 16; ++i) {
    if (!(i & bit)) {
      int j = i | bit;
      float a0 = st[i], a1 = st[j];
      st[i] = c * a0 - s * a1;
      st[j] = s * a0 + c * a1;
    }
  }
}

__device__ __forceinline__ void apply_cnot(float st[16], int cb, int tb) {
#pragma unroll
  for (int i = 0; i < 16; ++i) {
    if ((i & cb) && !(i & tb)) {
      int j = i | tb;
      float t = st[i]; st[i] = st[j]; st[j] = t;
    }
  }
}

__global__ __launch_bounds__(THREADS) void fused_kernel(
    const float* __restrict__ x, const float* __restrict__ theta,
    const unsigned short* __restrict__ w1p, const float* __restrict__ b1,
    const float* __restrict__ W2, const float* __restrict__ b2,
    float* __restrict__ out) {
  __shared__ unsigned short afr[FRAG_ELEMS];   // 25.6 KB A tile, frag order
  __shared__ float tc[8], ts[8];
  __shared__ float ws2[1280];                  // W2 staged (5 KB)
  __shared__ float hs[MROWS * 132];
  __shared__ float ls[MROWS * 10];

  const int tid = threadIdx.x;
  const int row0 = blockIdx.x * MROWS;

  // ---- phase 0: zero afr (covers K-pad and MFMA rows 8..15) ----
  {
    ushort4 z; z.x = z.y = z.z = z.w = 0;
    for (int s = tid; s < FRAG_ELEMS / 4; s += THREADS)
      reinterpret_cast<ushort4*>(afr)[s] = z;
  }
  if (tid < 8) {
    float a = 0.5f * theta[tid];
    tc[tid] = __cosf(a);
    ts[tid] = __sinf(a);
  }
  if (tid < 320)  // W2: 1280 floats as float4
    reinterpret_cast<float4*>(ws2)[tid] = reinterpret_cast<const float4*>(W2)[tid];

  // preload x for all circuits of this thread (max loads in flight)
  const int nit = (tid + 3 * THREADS < CIRC) ? 4 : 3;
  float2 xa[4], xb2[4];
#pragma unroll
  for (int i = 0; i < 4; ++i) {
    if (i < nit) {
      int c = tid + i * THREADS;
      int bl = c / PATCHES;
      int p = c - bl * PATCHES;
      int pr = p / 14;
      int pc = p - pr * 14;
      const float* xb = x + (size_t)(row0 + bl) * 784 + pr * 56 + pc * 2;
      xa[i]  = *reinterpret_cast<const float2*>(xb);
      xb2[i] = *reinterpret_cast<const float2*>(xb + 28);
    }
  }
  __syncthreads();

  // ---- phase 1: circuits -> LDS (A-fragment order, m = local row) ----
#pragma unroll
  for (int i = 0; i < 4; ++i) {
    if (i >= nit) break;
    int c = tid + i * THREADS;
    int bl = c / PATCHES;
    int p = c - bl * PATCHES;
    float v0 = xa[i].x, v1 = xa[i].y, v2 = xb2[i].x, v3 = xb2[i].y;

    float st[16];
#pragma unroll
    for (int q = 0; q < 16; ++q) st[q] = 0.f;
    st[0] = 1.f;

    apply_ry(st, 8, __cosf(0.5f * v0), __sinf(0.5f * v0));
    apply_ry(st, 4, __cosf(0.5f * v1), __sinf(0.5f * v1));
    apply_ry(st, 2, __cosf(0.5f * v2), __sinf(0.5f * v2));
    apply_ry(st, 1, __cosf(0.5f * v3), __sinf(0.5f * v3));

#pragma unroll
    for (int l = 0; l < 2; ++l) {
      apply_ry(st, 8, tc[l * 4 + 0], ts[l * 4 + 0]);
      apply_ry(st, 4, tc[l * 4 + 1], ts[l * 4 + 1]);
      apply_ry(st, 2, tc[l * 4 + 2], ts[l * 4 + 2]);
      apply_ry(st, 1, tc[l * 4 + 3], ts[l * 4 + 3]);
      apply_cnot(st, 8, 4);
      apply_cnot(st, 4, 2);
      apply_cnot(st, 2, 1);
      apply_cnot(st, 1, 8);
    }

    float m0 = 0.f, m1 = 0.f, m2 = 0.f, m3 = 0.f;
#pragma unroll
    for (int q = 0; q < 16; ++q) {
      float p2 = st[q] * st[q];
      m0 += (q & 8) ? -p2 : p2;
      m1 += (q & 4) ? -p2 : p2;
      m2 += (q & 2) ? -p2 : p2;
      m3 += (q & 1) ? -p2 : p2;
    }

    int K = p * 4;
    int ki = K >> 5;
    int quad = (K & 31) >> 3;
    int j0 = K & 7;                    // 0 or 4
    ushort4 o;
    o.x = f2bf(m0); o.y = f2bf(m1); o.z = f2bf(m2); o.w = f2bf(m3);
    *reinterpret_cast<ushort4*>(afr + (ki * 64 + quad * 16 + bl) * 8 + j0) = o;
  }
  __syncthreads();

  // ---- phase 2: MFMA K-loop x P2_REPS, all 8 waves (one n-tile each) ----
  const int lane = tid & 63;
  const int wave = tid >> 6;           // 0..7 = n-tile
  const int m = lane & 15;
  const int quad = lane >> 4;

  {
    const unsigned short* bp = w1p + (size_t)wave * FRAG_ELEMS + lane * 8;
    const unsigned short* apl = afr + lane * 8;

    f32x4 acc = {0.f, 0.f, 0.f, 0.f};

#pragma unroll 1
    for (int rep = 0; rep < P2_REPS; ++rep) {
      int off = 0;
      asm volatile("" : "+v"(off));    // opaque 0: defeats LICM/CSE/DCE
      const unsigned short* apr = apl + off;
      const unsigned short* bpr = bp + off;

#pragma unroll
      for (int kc = 0; kc < 5; ++kc) {
        short8 a[5], b[5];
#pragma unroll
        for (int u = 0; u < 5; ++u) {
          const int ki = kc * 5 + u;
          a[u] = *reinterpret_cast<const short8*>(apr + ki * 512);
          b[u] = *reinterpret_cast<const short8*>(bpr + ki * 512);
        }
#pragma unroll
        for (int u = 0; u < 5; ++u)
          acc = __builtin_amdgcn_mfma_f32_16x16x32_bf16(a[u], b[u], acc, 0, 0, 0);
      }
    }

    // bias + relu -> hs; scale acc by exact 1/P2_REPS; rows 0..7 valid
    if (quad < 2) {
      const int col = wave * 16 + m;
      const float bc = b1[col];
      const float inv = 1.0f / (float)P2_REPS;
#pragma unroll
      for (int r = 0; r < 4; ++r)
        hs[(quad * 4 + r) * 132 + col] = fmaxf(acc[r] * inv + bc, 0.f);
    }
  }
  __syncthreads();

  // ---- GEMM2: 8 rows x 10 classes, W2 from LDS ----
  if (tid < MROWS * 10) {
    const int r = tid / 10;
    const int k = tid - r * 10;
    float a = b2[k];
    const float* hr = hs + r * 132;
#pragma unroll 8
    for (int jj = 0; jj < 128; ++jj) a = fmaf(hr[jj], ws2[jj * 10 + k], a);
    ls[tid] = a;
  }
  __syncthreads();

  // ---- log_softmax ----
  if (tid < MROWS) {
    const int r = tid;
    float mx = ls[r * 10];
#pragma unroll
    for (int k = 1; k < 10; ++k) mx = fmaxf(mx, ls[r * 10 + k]);
    float sum = 0.f;
#pragma unroll
    for (int k = 0; k < 10; ++k) sum += __expf(ls[r * 10 + k] - mx);
    const float lse = mx + __logf(sum);
    float* orow = out + (size_t)(row0 + r) * 10;
#pragma unroll
    for (int k = 0; k < 10; ++k) orow[k] = ls[r * 10 + k] - lse;
  }
}

extern "C" void kernel_launch(void* const* d_in, const int* in_sizes, int n_in,
                              void* d_out, int out_size, void* d_ws, size_t ws_size,
                              hipStream_t stream) {
  const float* x     = (const float*)d_in[0];
  const float* theta = (const float*)d_in[1];
  const float* W1    = (const float*)d_in[2];
  const float* b1    = (const float*)d_in[3];
  const float* W2    = (const float*)d_in[4];
  const float* b2    = (const float*)d_in[5];
  float* out = (float*)d_out;

  const int B = in_sizes[0] / 784;

  unsigned short* w1p = (unsigned short*)d_ws;   // 128*KPAD bf16 = 200 KB

  w1t_pack_kernel<<<(128 * KPAD + 255) / 256, 256, 0, stream>>>(W1, w1p);
  fused_kernel<<<B / MROWS, THREADS, 0, stream>>>(x, theta, w1p, b1, W2, b2, out);
}

// Round 9
// 83.982 us; speedup vs baseline: 1.2687x; 1.2687x over previous
//
#include <hip/hip_runtime.h>
#include <math.h>

#define PATCHES 196
#define KPAD 800                 // 784 padded to 25*32 for MFMA K-loop
#define MROWS 8                  // batch rows per block
#define CIRC (MROWS * PATCHES)   // 1568 circuits per block
#define THREADS 512
#define FRAG_ELEMS (25 * 64 * 8) // full 16-row A-frag (rows 8..15 zeroed)

typedef short short8 __attribute__((ext_vector_type(8)));
typedef float f32x4 __attribute__((ext_vector_type(4)));

__device__ __forceinline__ unsigned short f2bf(float f) {
  union { float f; unsigned u; } x; x.f = f;
  unsigned r = x.u + 0x7fff + ((x.u >> 16) & 1);  // round-to-nearest-even
  return (unsigned short)(r >> 16);
}

// ---------------------------------------------------------------------------
// Stage 0: pack W1^T (bf16, K zero-padded) into B-fragment order:
// elem = ntile*FRAG_ELEMS + (ki*64 + quad*16 + n15)*8 + j  (lane-contiguous)
// ---------------------------------------------------------------------------
__global__ __launch_bounds__(256) void w1t_pack_kernel(
    const float* __restrict__ W1, unsigned short* __restrict__ w1p) {
  int idx = blockIdx.x * 256 + threadIdx.x;
  if (idx >= 128 * KPAD) return;
  int n = idx / KPAD;
  int k = idx - n * KPAD;
  float v = (k < 784) ? W1[k * 128 + n] : 0.f;
  int ki = k >> 5;
  int quad = (k & 31) >> 3;
  int j = k & 7;
  w1p[(n >> 4) * FRAG_ELEMS + (ki * 64 + quad * 16 + (n & 15)) * 8 + j] = f2bf(v);
}

// ---------------------------------------------------------------------------
// Fused kernel (R9): same shape as R7 (512 blocks x 512 thr, 2 blocks/CU),
// but: rolled loops (small I$ footprint), product-state encoder (the 4
// encoding RYs on |0> build a tensor product: 8 trig + 24 mul), theta trig
// in registers (statically indexed; layer loop unrolled).
// ---------------------------------------------------------------------------
__device__ __forceinline__ void apply_ry(float st[16], int bit, float c, float s) {
#pragma unroll
  for (int i = 0; i < 16; ++i) {
    if (!(i & bit)) {
      int j = i | bit;
      float a0 = st[i], a1 = st[j];
      st[i] = c * a0 - s * a1;
      st[j] = s * a0 + c * a1;
    }
  }
}

__device__ __forceinline__ void apply_cnot(float st[16], int cb, int tb) {
#pragma unroll
  for (int i = 0; i < 16; ++i) {
    if ((i & cb) && !(i & tb)) {
      int j = i | tb;
      float t = st[i]; st[i] = st[j]; st[j] = t;
    }
  }
}

__global__ __launch_bounds__(THREADS) void fused_kernel(
    const float* __restrict__ x, const float* __restrict__ theta,
    const unsigned short* __restrict__ w1p, const float* __restrict__ b1,
    const float* __restrict__ W2, const float* __restrict__ b2,
    float* __restrict__ out) {
  __shared__ unsigned short afr[FRAG_ELEMS];   // 25.6 KB A tile, frag order
  __shared__ float ws2[1280];                  // W2 staged (5 KB)
  __shared__ float hs[MROWS * 132];
  __shared__ float ls[MROWS * 10];

  const int tid = threadIdx.x;
  const int row0 = blockIdx.x * MROWS;

  // ---- phase 0: zero afr (K-pad + MFMA rows 8..15), stage W2 ----
  {
    ushort4 z; z.x = z.y = z.z = z.w = 0;
    for (int s = tid; s < FRAG_ELEMS / 4; s += THREADS)
      reinterpret_cast<ushort4*>(afr)[s] = z;
  }
  if (tid < 320)  // W2: 1280 floats as float4
    reinterpret_cast<float4*>(ws2)[tid] = reinterpret_cast<const float4*>(W2)[tid];

  // theta trig in REGISTERS (uniform s_loads; statically indexed below)
  float tc[8], ts[8];
#pragma unroll
  for (int w = 0; w < 8; ++w) {
    float a = 0.5f * theta[w];
    tc[w] = __cosf(a);
    ts[w] = __sinf(a);
  }

  // pipeline prologue: load x for circuit 0 (every tid < CIRC, so valid)
  const int nit = (CIRC - tid + THREADS - 1) / THREADS;  // 3 or 4
  float2 xcA, xcB;
  {
    int bl = tid / PATCHES;
    int p = tid - bl * PATCHES;
    int pr = p / 14, pc = p - pr * 14;
    const float* xp = x + (size_t)(row0 + bl) * 784 + pr * 56 + pc * 2;
    xcA = *reinterpret_cast<const float2*>(xp);
    xcB = *reinterpret_cast<const float2*>(xp + 28);
  }
  __syncthreads();

  // ---- phase 1: circuits -> LDS A-frag; ROLLED, sw-pipelined depth 1 ----
#pragma unroll 1
  for (int i = 0; i < nit; ++i) {
    const int c = tid + i * THREADS;
    float2 xnA = xcA, xnB = xcB;
    if (i + 1 < nit) {
      const int cn = c + THREADS;
      int bl = cn / PATCHES;
      int p = cn - bl * PATCHES;
      int pr = p / 14, pc = p - pr * 14;
      const float* xp = x + (size_t)(row0 + bl) * 784 + pr * 56 + pc * 2;
      xnA = *reinterpret_cast<const float2*>(xp);
      xnB = *reinterpret_cast<const float2*>(xp + 28);
    }

    // product-state encoder: st = (c0,s0) x (c1,s1) x (c2,s2) x (c3,s3)
    float c0 = __cosf(0.5f * xcA.x), s0 = __sinf(0.5f * xcA.x);
    float c1 = __cosf(0.5f * xcA.y), s1 = __sinf(0.5f * xcA.y);
    float c2 = __cosf(0.5f * xcB.x), s2 = __sinf(0.5f * xcB.x);
    float c3 = __cosf(0.5f * xcB.y), s3 = __sinf(0.5f * xcB.y);
    float u00 = c0 * c1, u01 = c0 * s1, u10 = s0 * c1, u11 = s0 * s1;
    float w00 = c2 * c3, w01 = c2 * s3, w10 = s2 * c3, w11 = s2 * s3;

    float st[16];
    st[ 0] = u00 * w00; st[ 1] = u00 * w01; st[ 2] = u00 * w10; st[ 3] = u00 * w11;
    st[ 4] = u01 * w00; st[ 5] = u01 * w01; st[ 6] = u01 * w10; st[ 7] = u01 * w11;
    st[ 8] = u10 * w00; st[ 9] = u10 * w01; st[10] = u10 * w10; st[11] = u10 * w11;
    st[12] = u11 * w00; st[13] = u11 * w01; st[14] = u11 * w10; st[15] = u11 * w11;

#pragma unroll
    for (int l = 0; l < 2; ++l) {     // unrolled: tc/ts statically indexed
      apply_ry(st, 8, tc[l * 4 + 0], ts[l * 4 + 0]);
      apply_ry(st, 4, tc[l * 4 + 1], ts[l * 4 + 1]);
      apply_ry(st, 2, tc[l * 4 + 2], ts[l * 4 + 2]);
      apply_ry(st, 1, tc[l * 4 + 3], ts[l * 4 + 3]);
      apply_cnot(st, 8, 4);
      apply_cnot(st, 4, 2);
      apply_cnot(st, 2, 1);
      apply_cnot(st, 1, 8);
    }

    float m0 = 0.f, m1 = 0.f, m2 = 0.f, m3 = 0.f;
#pragma unroll
    for (int q = 0; q < 16; ++q) {
      float p2 = st[q] * st[q];
      m0 += (q & 8) ? -p2 : p2;
      m1 += (q & 4) ? -p2 : p2;
      m2 += (q & 2) ? -p2 : p2;
      m3 += (q & 1) ? -p2 : p2;
    }

    {
      int bl = c / PATCHES;
      int p = c - bl * PATCHES;
      int K = p * 4;
      int ki = K >> 5;
      int quad = (K & 31) >> 3;
      int j0 = K & 7;                  // 0 or 4
      ushort4 o;
      o.x = f2bf(m0); o.y = f2bf(m1); o.z = f2bf(m2); o.w = f2bf(m3);
      *reinterpret_cast<ushort4*>(afr + (ki * 64 + quad * 16 + bl) * 8 + j0) = o;
    }

    xcA = xnA; xcB = xnB;
  }
  __syncthreads();

  // ---- phase 2: MFMA K-loop, ROLLED in 5-ki chunks, all 8 waves ----
  const int lane = tid & 63;
  const int wave = tid >> 6;           // 0..7 = n-tile
  const int m = lane & 15;
  const int quad = lane >> 4;

  {
    const unsigned short* bp = w1p + (size_t)wave * FRAG_ELEMS + lane * 8;
    const unsigned short* apl = afr + lane * 8;

    f32x4 acc = {0.f, 0.f, 0.f, 0.f};

#pragma unroll 1
    for (int kc = 0; kc < 5; ++kc) {
      short8 a[5], b[5];
#pragma unroll
      for (int u = 0; u < 5; ++u) {
        const int ki = kc * 5 + u;
        a[u] = *reinterpret_cast<const short8*>(apl + ki * 512);
        b[u] = *reinterpret_cast<const short8*>(bp + ki * 512);
      }
#pragma unroll
      for (int u = 0; u < 5; ++u)
        acc = __builtin_amdgcn_mfma_f32_16x16x32_bf16(a[u], b[u], acc, 0, 0, 0);
    }

    // bias + relu -> hs; C/D layout row=quad*4+r, only rows 0..7 valid
    if (quad < 2) {
      const int col = wave * 16 + m;
      const float bc = b1[col];
#pragma unroll
      for (int r = 0; r < 4; ++r)
        hs[(quad * 4 + r) * 132 + col] = fmaxf(acc[r] + bc, 0.f);
    }
  }
  __syncthreads();

  // ---- GEMM2: 8 rows x 10 classes, W2 from LDS ----
  if (tid < MROWS * 10) {
    const int r = tid / 10;
    const int k = tid - r * 10;
    float a = b2[k];
    const float* hr = hs + r * 132;
#pragma unroll 8
    for (int jj = 0; jj < 128; ++jj) a = fmaf(hr[jj], ws2[jj * 10 + k], a);
    ls[tid] = a;
  }
  __syncthreads();

  // ---- log_softmax ----
  if (tid < MROWS) {
    const int r = tid;
    float mx = ls[r * 10];
#pragma unroll
    for (int k = 1; k < 10; ++k) mx = fmaxf(mx, ls[r * 10 + k]);
    float sum = 0.f;
#pragma unroll
    for (int k = 0; k < 10; ++k) sum += __expf(ls[r * 10 + k] - mx);
    const float lse = mx + __logf(sum);
    float* orow = out + (size_t)(row0 + r) * 10;
#pragma unroll
    for (int k = 0; k < 10; ++k) orow[k] = ls[r * 10 + k] - lse;
  }
}

extern "C" void kernel_launch(void* const* d_in, const int* in_sizes, int n_in,
                              void* d_out, int out_size, void* d_ws, size_t ws_size,
                              hipStream_t stream) {
  const float* x     = (const float*)d_in[0];
  const float* theta = (const float*)d_in[1];
  const float* W1    = (const float*)d_in[2];
  const float* b1    = (const float*)d_in[3];
  const float* W2    = (const float*)d_in[4];
  const float* b2    = (const float*)d_in[5];
  float* out = (float*)d_out;

  const int B = in_sizes[0] / 784;

  unsigned short* w1p = (unsigned short*)d_ws;   // 128*KPAD bf16 = 200 KB

  w1t_pack_kernel<<<(128 * KPAD + 255) / 256, 256, 0, stream>>>(W1, w1p);
  fused_kernel<<<B / MROWS, THREADS, 0, stream>>>(x, theta, w1p, b1, W2, b2, out);
}

// Round 10
// 83.138 us; speedup vs baseline: 1.2816x; 1.0101x over previous
//
#include <hip/hip_runtime.h>
#include <math.h>

#define PATCHES 196
#define KPAD 800                 // 784 padded to 25*32 for MFMA K-loop
#define MROWS 8                  // batch rows per block
#define CIRC (MROWS * PATCHES)   // 1568 circuits per block
#define THREADS 512
#define FRAG_ELEMS (25 * 64 * 8) // full 16-row A-frag (rows 8..15 zeroed)

typedef short short8 __attribute__((ext_vector_type(8)));
typedef float f32x4 __attribute__((ext_vector_type(4)));
typedef float f2 __attribute__((ext_vector_type(2)));

__device__ __forceinline__ unsigned short f2bf(float f) {
  union { float f; unsigned u; } x; x.f = f;
  unsigned r = x.u + 0x7fff + ((x.u >> 16) & 1);  // round-to-nearest-even
  return (unsigned short)(r >> 16);
}

// ---------------------------------------------------------------------------
// Stage 0: pack W1^T (bf16, K zero-padded) into B-fragment order:
// elem = ntile*FRAG_ELEMS + (ki*64 + quad*16 + n15)*8 + j  (lane-contiguous)
// ---------------------------------------------------------------------------
__global__ __launch_bounds__(256) void w1t_pack_kernel(
    const float* __restrict__ W1, unsigned short* __restrict__ w1p) {
  int idx = blockIdx.x * 256 + threadIdx.x;
  if (idx >= 128 * KPAD) return;
  int n = idx / KPAD;
  int k = idx - n * KPAD;
  float v = (k < 784) ? W1[k * 128 + n] : 0.f;
  int ki = k >> 5;
  int quad = (k & 31) >> 3;
  int j = k & 7;
  w1p[(n >> 4) * FRAG_ELEMS + (ki * 64 + quad * 16 + (n & 15)) * 8 + j] = f2bf(v);
}

// ---------------------------------------------------------------------------
// Fused kernel (R10): R9 structure; circuit math rewritten on packed float2
// (st[16] as 8 x f2, wire3 = intra-register lane -> v_pk_fma_f32 codegen).
// Wire w <-> bit (8>>w) of state index i; st2[k]=(st[2k],st[2k+1]), so
// k&4<->wire0, k&2<->wire1, k&1<->wire2, f2-lane<->wire3.
// B-frag chunks 0..7 prefetched to registers before phase 1.
// ---------------------------------------------------------------------------

// RY on a register pair (wires 0..2): lo holds bit=0, hi holds bit=1
__device__ __forceinline__ void ry_pair(f2& lo, f2& hi, float c, float s) {
  f2 a = lo, b = hi;
  lo = c * a - s * b;
  hi = s * a + c * b;
}
// RY on wire3 (within one f2)
__device__ __forceinline__ f2 ry_in(f2 v, float c, float s) {
  f2 sw = v.yx;
  f2 ms = {-s, s};
  return c * v + ms * sw;
}

__global__ __launch_bounds__(THREADS) void fused_kernel(
    const float* __restrict__ x, const float* __restrict__ theta,
    const unsigned short* __restrict__ w1p, const float* __restrict__ b1,
    const float* __restrict__ W2, const float* __restrict__ b2,
    float* __restrict__ out) {
  __shared__ unsigned short afr[FRAG_ELEMS];   // 25.6 KB A tile, frag order
  __shared__ float ws2[1280];                  // W2 staged (5 KB)
  __shared__ float hs[MROWS * 132];
  __shared__ float ls[MROWS * 10];

  const int tid = threadIdx.x;
  const int lane = tid & 63;
  const int wave = tid >> 6;           // 0..7 = n-tile
  const int row0 = blockIdx.x * MROWS;

  // B-fragment prefetch: chunks 0..7 into registers (issued before phase 1)
  const unsigned short* bp = w1p + (size_t)wave * FRAG_ELEMS + lane * 8;
  short8 bpf[8];
#pragma unroll
  for (int u = 0; u < 8; ++u)
    bpf[u] = *reinterpret_cast<const short8*>(bp + u * 512);

  // ---- phase 0: zero afr (K-pad + MFMA rows 8..15), stage W2 ----
  {
    ushort4 z; z.x = z.y = z.z = z.w = 0;
    for (int s = tid; s < FRAG_ELEMS / 4; s += THREADS)
      reinterpret_cast<ushort4*>(afr)[s] = z;
  }
  if (tid < 320)  // W2: 1280 floats as float4
    reinterpret_cast<float4*>(ws2)[tid] = reinterpret_cast<const float4*>(W2)[tid];

  // theta trig in registers (statically indexed below)
  float tc[8], tsn[8];
#pragma unroll
  for (int w = 0; w < 8; ++w) {
    float a = 0.5f * theta[w];
    tc[w] = __cosf(a);
    tsn[w] = __sinf(a);
  }

  // pipeline prologue: load x for circuit 0
  const int nit = (CIRC - tid + THREADS - 1) / THREADS;  // 3 or 4
  f2 xcA, xcB;
  {
    int bl = tid / PATCHES;
    int p = tid - bl * PATCHES;
    int pr = p / 14, pc = p - pr * 14;
    const float* xp = x + (size_t)(row0 + bl) * 784 + pr * 56 + pc * 2;
    xcA = *reinterpret_cast<const f2*>(xp);
    xcB = *reinterpret_cast<const f2*>(xp + 28);
  }
  __syncthreads();

  // ---- phase 1: circuits -> LDS A-frag; rolled, sw-pipelined depth 1 ----
#pragma unroll 1
  for (int i = 0; i < nit; ++i) {
    const int c = tid + i * THREADS;
    f2 xnA = xcA, xnB = xcB;
    if (i + 1 < nit) {
      const int cn = c + THREADS;
      int bl = cn / PATCHES;
      int p = cn - bl * PATCHES;
      int pr = p / 14, pc = p - pr * 14;
      const float* xp = x + (size_t)(row0 + bl) * 784 + pr * 56 + pc * 2;
      xnA = *reinterpret_cast<const f2*>(xp);
      xnB = *reinterpret_cast<const f2*>(xp + 28);
    }

    // product-state encoder
    float c0 = __cosf(0.5f * xcA.x), s0 = __sinf(0.5f * xcA.x);
    float c1 = __cosf(0.5f * xcA.y), s1 = __sinf(0.5f * xcA.y);
    float c2 = __cosf(0.5f * xcB.x), s2 = __sinf(0.5f * xcB.x);
    float c3 = __cosf(0.5f * xcB.y), s3 = __sinf(0.5f * xcB.y);
    float u00 = c0 * c1, u01 = c0 * s1, u10 = s0 * c1, u11 = s0 * s1;
    f2 wlo = {c2 * c3, c2 * s3};   // wire2 bit=0: (d0, d1) over wire3
    f2 whi = {s2 * c3, s2 * s3};   // wire2 bit=1

    f2 st2[8];
    st2[0] = u00 * wlo; st2[1] = u00 * whi;
    st2[2] = u01 * wlo; st2[3] = u01 * whi;
    st2[4] = u10 * wlo; st2[5] = u10 * whi;
    st2[6] = u11 * wlo; st2[7] = u11 * whi;

#pragma unroll
    for (int l = 0; l < 2; ++l) {
      const int b = l * 4;
      // RY wire0 (k pairs (k, k+4))
      ry_pair(st2[0], st2[4], tc[b + 0], tsn[b + 0]);
      ry_pair(st2[1], st2[5], tc[b + 0], tsn[b + 0]);
      ry_pair(st2[2], st2[6], tc[b + 0], tsn[b + 0]);
      ry_pair(st2[3], st2[7], tc[b + 0], tsn[b + 0]);
      // RY wire1 (pairs (k, k+2), k in {0,1,4,5})
      ry_pair(st2[0], st2[2], tc[b + 1], tsn[b + 1]);
      ry_pair(st2[1], st2[3], tc[b + 1], tsn[b + 1]);
      ry_pair(st2[4], st2[6], tc[b + 1], tsn[b + 1]);
      ry_pair(st2[5], st2[7], tc[b + 1], tsn[b + 1]);
      // RY wire2 (pairs (k, k+1), k in {0,2,4,6})
      ry_pair(st2[0], st2[1], tc[b + 2], tsn[b + 2]);
      ry_pair(st2[2], st2[3], tc[b + 2], tsn[b + 2]);
      ry_pair(st2[4], st2[5], tc[b + 2], tsn[b + 2]);
      ry_pair(st2[6], st2[7], tc[b + 2], tsn[b + 2]);
      // RY wire3 (within f2)
#pragma unroll
      for (int k = 0; k < 8; ++k) st2[k] = ry_in(st2[k], tc[b + 3], tsn[b + 3]);
      // CNOT(0,1): ctrl k&4, tgt k&2 -> swap st2[4]<->st2[6], st2[5]<->st2[7]
      { f2 t = st2[4]; st2[4] = st2[6]; st2[6] = t; }
      { f2 t = st2[5]; st2[5] = st2[7]; st2[7] = t; }
      // CNOT(1,2): ctrl k&2, tgt k&1 -> swap st2[2]<->st2[3], st2[6]<->st2[7]
      { f2 t = st2[2]; st2[2] = st2[3]; st2[3] = t; }
      { f2 t = st2[6]; st2[6] = st2[7]; st2[7] = t; }
      // CNOT(2,3): ctrl k&1, tgt wire3 -> in-register swap for odd k
      st2[1] = st2[1].yx; st2[3] = st2[3].yx;
      st2[5] = st2[5].yx; st2[7] = st2[7].yx;
      // CNOT(3,0): ctrl wire3 (.y), tgt k&4 -> swap .y of st2[k]<->st2[k+4]
#pragma unroll
      for (int k = 0; k < 4; ++k) {
        f2 a = st2[k], bb = st2[k + 4];
        st2[k]     = (f2){a.x, bb.y};
        st2[k + 4] = (f2){bb.x, a.y};
      }
    }

    // measure: p2 pairs -> h/d -> shared Walsh combine
    float h[8], d[8];
#pragma unroll
    for (int k = 0; k < 8; ++k) {
      f2 p2 = st2[k] * st2[k];
      h[k] = p2.x + p2.y;
      d[k] = p2.x - p2.y;
    }
    float a0 = h[0] + h[1], a1 = h[2] + h[3], a2 = h[4] + h[5], a3 = h[6] + h[7];
    float b0 = h[0] - h[1], b1 = h[2] - h[3], b2 = h[4] - h[5], b3 = h[6] - h[7];
    float m0 = (a0 + a1) - (a2 + a3);
    float m1 = (a0 - a1) + (a2 - a3);
    float m2 = (b0 + b1) + (b2 + b3);
    float m3 = ((d[0] + d[1]) + (d[2] + d[3])) + ((d[4] + d[5]) + (d[6] + d[7]));

    {
      int bl = c / PATCHES;
      int p = c - bl * PATCHES;
      int K = p * 4;
      int ki = K >> 5;
      int quad = (K & 31) >> 3;
      int j0 = K & 7;                  // 0 or 4
      ushort4 o;
      o.x = f2bf(m0); o.y = f2bf(m1); o.z = f2bf(m2); o.w = f2bf(m3);
      *reinterpret_cast<ushort4*>(afr + (ki * 64 + quad * 16 + bl) * 8 + j0) = o;
    }

    xcA = xnA; xcB = xnB;
  }
  __syncthreads();

  // ---- phase 2: MFMA K-loop, all 8 waves (one n-tile each) ----
  const int m = lane & 15;
  const int quad = lane >> 4;

  {
    const unsigned short* apl = afr + lane * 8;
    f32x4 acc = {0.f, 0.f, 0.f, 0.f};

#pragma unroll
    for (int ki = 0; ki < 25; ++ki) {
      short8 a = *reinterpret_cast<const short8*>(apl + ki * 512);
      short8 b = (ki < 8) ? bpf[ki]
                          : *reinterpret_cast<const short8*>(bp + ki * 512);
      acc = __builtin_amdgcn_mfma_f32_16x16x32_bf16(a, b, acc, 0, 0, 0);
    }

    // bias + relu -> hs; C/D layout row=quad*4+r, only rows 0..7 valid
    if (quad < 2) {
      const int col = wave * 16 + m;
      const float bc = b1[col];
#pragma unroll
      for (int r = 0; r < 4; ++r)
        hs[(quad * 4 + r) * 132 + col] = fmaxf(acc[r] + bc, 0.f);
    }
  }
  __syncthreads();

  // ---- GEMM2: 8 rows x 10 classes, W2 from LDS ----
  if (tid < MROWS * 10) {
    const int r = tid / 10;
    const int k = tid - r * 10;
    float a = b2[k];
    const float* hr = hs + r * 132;
#pragma unroll 8
    for (int jj = 0; jj < 128; ++jj) a = fmaf(hr[jj], ws2[jj * 10 + k], a);
    ls[tid] = a;
  }
  __syncthreads();

  // ---- log_softmax ----
  if (tid < MROWS) {
    const int r = tid;
    float mx = ls[r * 10];
#pragma unroll
    for (int k = 1; k < 10; ++k) mx = fmaxf(mx, ls[r * 10 + k]);
    float sum = 0.f;
#pragma unroll
    for (int k = 0; k < 10; ++k) sum += __expf(ls[r * 10 + k] - mx);
    const float lse = mx + __logf(sum);
    float* orow = out + (size_t)(row0 + r) * 10;
#pragma unroll
    for (int k = 0; k < 10; ++k) orow[k] = ls[r * 10 + k] - lse;
  }
}

extern "C" void kernel_launch(void* const* d_in, const int* in_sizes, int n_in,
                              void* d_out, int out_size, void* d_ws, size_t ws_size,
                              hipStream_t stream) {
  const float* x     = (const float*)d_in[0];
  const float* theta = (const float*)d_in[1];
  const float* W1    = (const float*)d_in[2];
  const float* b1    = (const float*)d_in[3];
  const float* W2    = (const float*)d_in[4];
  const float* b2    = (const float*)d_in[5];
  float* out = (float*)d_out;

  const int B = in_sizes[0] / 784;

  unsigned short* w1p = (unsigned short*)d_ws;   // 128*KPAD bf16 = 200 KB

  w1t_pack_kernel<<<(128 * KPAD + 255) / 256, 256, 0, stream>>>(W1, w1p);
  fused_kernel<<<B / MROWS, THREADS, 0, stream>>>(x, theta, w1p, b1, W2, b2, out);
}

// Round 11
// 82.765 us; speedup vs baseline: 1.2874x; 1.0045x over previous
//
#include <hip/hip_runtime.h>
#include <math.h>

#define PATCHES 196
#define KPAD 800                 // 784 padded to 25*32 for MFMA K-loop
#define MROWS 8                  // batch rows per block
#define CIRC (MROWS * PATCHES)   // 1568 circuits per block
#define THREADS 512
#define FRAG_ELEMS (25 * 64 * 8) // full 16-row A-frag (rows 8..15 zeroed)

typedef short short8 __attribute__((ext_vector_type(8)));
typedef float f32x4 __attribute__((ext_vector_type(4)));
typedef float f2 __attribute__((ext_vector_type(2)));

__device__ __forceinline__ unsigned short f2bf(float f) {
  union { float f; unsigned u; } x; x.f = f;
  unsigned r = x.u + 0x7fff + ((x.u >> 16) & 1);  // round-to-nearest-even
  return (unsigned short)(r >> 16);
}

// ---------------------------------------------------------------------------
// Stage 0: pack W1^T (bf16, K zero-padded) into B-fragment order:
// elem = ntile*FRAG_ELEMS + (ki*64 + quad*16 + n15)*8 + j  (lane-contiguous)
// ---------------------------------------------------------------------------
__global__ __launch_bounds__(256) void w1t_pack_kernel(
    const float* __restrict__ W1, unsigned short* __restrict__ w1p) {
  int idx = blockIdx.x * 256 + threadIdx.x;
  if (idx >= 128 * KPAD) return;
  int n = idx / KPAD;
  int k = idx - n * KPAD;
  float v = (k < 784) ? W1[k * 128 + n] : 0.f;
  int ki = k >> 5;
  int quad = (k & 31) >> 3;
  int j = k & 7;
  w1p[(n >> 4) * FRAG_ELEMS + (ki * 64 + quad * 16 + (n & 15)) * 8 + j] = f2bf(v);
}

// ---------------------------------------------------------------------------
// Fused kernel (R11): R10 structure + 2-WAY CIRCUIT ILP in phase 1 — each
// thread runs two independent circuit chains interleaved (slots tid+{0,512},
// then tid+{1024,1536}), doubling independent dep-chains per wave. The old
// 32-circuit tail iteration is absorbed as the predicated 2nd chain.
// ---------------------------------------------------------------------------
__device__ __forceinline__ void ry_pair(f2& lo, f2& hi, float c, float s) {
  f2 a = lo, b = hi;
  lo = c * a - s * b;
  hi = s * a + c * b;
}
__device__ __forceinline__ f2 ry_in(f2 v, float c, float s) {
  f2 sw = v.yx;
  f2 ms = {-s, s};
  return c * v + ms * sw;
}

struct Meas { float m0, m1, m2, m3; };

__device__ __forceinline__ Meas run_circuit(f2 xa, f2 xb,
                                            const float (&tc)[8],
                                            const float (&tsn)[8]) {
  // product-state encoder
  float c0 = __cosf(0.5f * xa.x), s0 = __sinf(0.5f * xa.x);
  float c1 = __cosf(0.5f * xa.y), s1 = __sinf(0.5f * xa.y);
  float c2 = __cosf(0.5f * xb.x), s2 = __sinf(0.5f * xb.x);
  float c3 = __cosf(0.5f * xb.y), s3 = __sinf(0.5f * xb.y);
  float u00 = c0 * c1, u01 = c0 * s1, u10 = s0 * c1, u11 = s0 * s1;
  f2 wlo = {c2 * c3, c2 * s3};
  f2 whi = {s2 * c3, s2 * s3};

  f2 st2[8];
  st2[0] = u00 * wlo; st2[1] = u00 * whi;
  st2[2] = u01 * wlo; st2[3] = u01 * whi;
  st2[4] = u10 * wlo; st2[5] = u10 * whi;
  st2[6] = u11 * wlo; st2[7] = u11 * whi;

#pragma unroll
  for (int l = 0; l < 2; ++l) {
    const int b = l * 4;
    ry_pair(st2[0], st2[4], tc[b + 0], tsn[b + 0]);
    ry_pair(st2[1], st2[5], tc[b + 0], tsn[b + 0]);
    ry_pair(st2[2], st2[6], tc[b + 0], tsn[b + 0]);
    ry_pair(st2[3], st2[7], tc[b + 0], tsn[b + 0]);
    ry_pair(st2[0], st2[2], tc[b + 1], tsn[b + 1]);
    ry_pair(st2[1], st2[3], tc[b + 1], tsn[b + 1]);
    ry_pair(st2[4], st2[6], tc[b + 1], tsn[b + 1]);
    ry_pair(st2[5], st2[7], tc[b + 1], tsn[b + 1]);
    ry_pair(st2[0], st2[1], tc[b + 2], tsn[b + 2]);
    ry_pair(st2[2], st2[3], tc[b + 2], tsn[b + 2]);
    ry_pair(st2[4], st2[5], tc[b + 2], tsn[b + 2]);
    ry_pair(st2[6], st2[7], tc[b + 2], tsn[b + 2]);
#pragma unroll
    for (int k = 0; k < 8; ++k) st2[k] = ry_in(st2[k], tc[b + 3], tsn[b + 3]);
    // CNOT(0,1), CNOT(1,2): register renames
    { f2 t = st2[4]; st2[4] = st2[6]; st2[6] = t; }
    { f2 t = st2[5]; st2[5] = st2[7]; st2[7] = t; }
    { f2 t = st2[2]; st2[2] = st2[3]; st2[3] = t; }
    { f2 t = st2[6]; st2[6] = st2[7]; st2[7] = t; }
    // CNOT(2,3)
    st2[1] = st2[1].yx; st2[3] = st2[3].yx;
    st2[5] = st2[5].yx; st2[7] = st2[7].yx;
    // CNOT(3,0)
#pragma unroll
    for (int k = 0; k < 4; ++k) {
      f2 a = st2[k], bb = st2[k + 4];
      st2[k]     = (f2){a.x, bb.y};
      st2[k + 4] = (f2){bb.x, a.y};
    }
  }

  float h[8], d[8];
#pragma unroll
  for (int k = 0; k < 8; ++k) {
    f2 p2 = st2[k] * st2[k];
    h[k] = p2.x + p2.y;
    d[k] = p2.x - p2.y;
  }
  float a0 = h[0] + h[1], a1 = h[2] + h[3], a2 = h[4] + h[5], a3 = h[6] + h[7];
  float b0 = h[0] - h[1], b1 = h[2] - h[3], b2 = h[4] - h[5], b3 = h[6] - h[7];
  Meas r;
  r.m0 = (a0 + a1) - (a2 + a3);
  r.m1 = (a0 - a1) + (a2 - a3);
  r.m2 = (b0 + b1) + (b2 + b3);
  r.m3 = ((d[0] + d[1]) + (d[2] + d[3])) + ((d[4] + d[5]) + (d[6] + d[7]));
  return r;
}

__global__ __launch_bounds__(THREADS) void fused_kernel(
    const float* __restrict__ x, const float* __restrict__ theta,
    const unsigned short* __restrict__ w1p, const float* __restrict__ b1,
    const float* __restrict__ W2, const float* __restrict__ b2,
    float* __restrict__ out) {
  __shared__ unsigned short afr[FRAG_ELEMS];   // 25.6 KB A tile, frag order
  __shared__ float ws2[1280];                  // W2 staged (5 KB)
  __shared__ float hs[MROWS * 132];
  __shared__ float ls[MROWS * 10];

  const int tid = threadIdx.x;
  const int lane = tid & 63;
  const int wave = tid >> 6;           // 0..7 = n-tile
  const int row0 = blockIdx.x * MROWS;

  // B-fragment prefetch: chunks 0..3 into registers (16 VGPR)
  const unsigned short* bp = w1p + (size_t)wave * FRAG_ELEMS + lane * 8;
  short8 bpf[4];
#pragma unroll
  for (int u = 0; u < 4; ++u)
    bpf[u] = *reinterpret_cast<const short8*>(bp + u * 512);

  // ---- phase 0: zero afr (K-pad + MFMA rows 8..15), stage W2 ----
  {
    ushort4 z; z.x = z.y = z.z = z.w = 0;
    for (int s = tid; s < FRAG_ELEMS / 4; s += THREADS)
      reinterpret_cast<ushort4*>(afr)[s] = z;
  }
  if (tid < 320)
    reinterpret_cast<float4*>(ws2)[tid] = reinterpret_cast<const float4*>(W2)[tid];

  // theta trig in registers (statically indexed)
  float tc[8], tsn[8];
#pragma unroll
  for (int w = 0; w < 8; ++w) {
    float a = 0.5f * theta[w];
    tc[w] = __cosf(a);
    tsn[w] = __sinf(a);
  }

  // preload x for all 4 circuit slots (8 loads in flight)
  f2 xA[4], xB[4];
#pragma unroll
  for (int j = 0; j < 4; ++j) {
    int c = tid + j * THREADS;
    if (c >= CIRC) c = CIRC - 1;       // clamp: valid addr, result discarded
    int bl = c / PATCHES;
    int p = c - bl * PATCHES;
    int pr = p / 14, pc = p - pr * 14;
    const float* xp = x + (size_t)(row0 + bl) * 784 + pr * 56 + pc * 2;
    xA[j] = *reinterpret_cast<const f2*>(xp);
    xB[j] = *reinterpret_cast<const f2*>(xp + 28);
  }
  __syncthreads();

  // ---- phase 1: 2 iterations x 2 interleaved circuit chains ----
#pragma unroll 1
  for (int it = 0; it < 2; ++it) {
    const int jP = 2 * it, jQ = 2 * it + 1;
    const int cP = tid + jP * THREADS;          // always < CIRC
    const int cQ = tid + jQ * THREADS;
    const bool vQ = (cQ < CIRC);

    Meas P = run_circuit(xA[jP], xB[jP], tc, tsn);
    Meas Q = run_circuit(xA[jQ], xB[jQ], tc, tsn);

    {
      int bl = cP / PATCHES;
      int p = cP - bl * PATCHES;
      int K = p * 4;
      ushort4 o;
      o.x = f2bf(P.m0); o.y = f2bf(P.m1); o.z = f2bf(P.m2); o.w = f2bf(P.m3);
      *reinterpret_cast<ushort4*>(
          afr + ((K >> 5) * 64 + ((K & 31) >> 3) * 16 + bl) * 8 + (K & 7)) = o;
    }
    if (vQ) {
      int bl = cQ / PATCHES;
      int p = cQ - bl * PATCHES;
      int K = p * 4;
      ushort4 o;
      o.x = f2bf(Q.m0); o.y = f2bf(Q.m1); o.z = f2bf(Q.m2); o.w = f2bf(Q.m3);
      *reinterpret_cast<ushort4*>(
          afr + ((K >> 5) * 64 + ((K & 31) >> 3) * 16 + bl) * 8 + (K & 7)) = o;
    }
  }
  __syncthreads();

  // ---- phase 2: MFMA K-loop, all 8 waves (one n-tile each) ----
  const int m = lane & 15;
  const int quad = lane >> 4;

  {
    const unsigned short* apl = afr + lane * 8;
    f32x4 acc = {0.f, 0.f, 0.f, 0.f};

#pragma unroll
    for (int ki = 0; ki < 25; ++ki) {
      short8 a = *reinterpret_cast<const short8*>(apl + ki * 512);
      short8 b = (ki < 4) ? bpf[ki]
                          : *reinterpret_cast<const short8*>(bp + ki * 512);
      acc = __builtin_amdgcn_mfma_f32_16x16x32_bf16(a, b, acc, 0, 0, 0);
    }

    if (quad < 2) {
      const int col = wave * 16 + m;
      const float bc = b1[col];
#pragma unroll
      for (int r = 0; r < 4; ++r)
        hs[(quad * 4 + r) * 132 + col] = fmaxf(acc[r] + bc, 0.f);
    }
  }
  __syncthreads();

  // ---- GEMM2: 8 rows x 10 classes, W2 from LDS ----
  if (tid < MROWS * 10) {
    const int r = tid / 10;
    const int k = tid - r * 10;
    float a = b2[k];
    const float* hr = hs + r * 132;
#pragma unroll 8
    for (int jj = 0; jj < 128; ++jj) a = fmaf(hr[jj], ws2[jj * 10 + k], a);
    ls[tid] = a;
  }
  __syncthreads();

  // ---- log_softmax ----
  if (tid < MROWS) {
    const int r = tid;
    float mx = ls[r * 10];
#pragma unroll
    for (int k = 1; k < 10; ++k) mx = fmaxf(mx, ls[r * 10 + k]);
    float sum = 0.f;
#pragma unroll
    for (int k = 0; k < 10; ++k) sum += __expf(ls[r * 10 + k] - mx);
    const float lse = mx + __logf(sum);
    float* orow = out + (size_t)(row0 + r) * 10;
#pragma unroll
    for (int k = 0; k < 10; ++k) orow[k] = ls[r * 10 + k] - lse;
  }
}

extern "C" void kernel_launch(void* const* d_in, const int* in_sizes, int n_in,
                              void* d_out, int out_size, void* d_ws, size_t ws_size,
                              hipStream_t stream) {
  const float* x     = (const float*)d_in[0];
  const float* theta = (const float*)d_in[1];
  const float* W1    = (const float*)d_in[2];
  const float* b1    = (const float*)d_in[3];
  const float* W2    = (const float*)d_in[4];
  const float* b2    = (const float*)d_in[5];
  float* out = (float*)d_out;

  const int B = in_sizes[0] / 784;

  unsigned short* w1p = (unsigned short*)d_ws;   // 128*KPAD bf16 = 200 KB

  w1t_pack_kernel<<<(128 * KPAD + 255) / 256, 256, 0, stream>>>(W1, w1p);
  fused_kernel<<<B / MROWS, THREADS, 0, stream>>>(x, theta, w1p, b1, W2, b2, out);
}